// Round 3
// baseline (290.997 us; speedup 1.0000x reference)
//
#include <hip/hip_runtime.h>

#define TBL 4096

// ws float layout (produced by precompute_kernel)
#define WS_S    0
#define WS_AT   64
#define WS_BQT  (64 + 512)
#define WS_CT   (64 + 1024)
#define WS_C0   (64 + 1024 + 64)

typedef __attribute__((ext_vector_type(8))) short bf16x8;
typedef __attribute__((ext_vector_type(4))) float f32x4;

__device__ inline short f2bf(float f) {
    union { float f; unsigned u; } v; v.f = f;
    unsigned r = v.u + 0x7fffu + ((v.u >> 16) & 1u);
    return (short)(r >> 16);
}

__device__ inline bf16x8 pack8(const float* x) {
    bf16x8 r;
    #pragma unroll
    for (int i = 0; i < 8; ++i) r[i] = f2bf(x[i]);
    return r;
}

__device__ inline bf16x8 loadpack(const float* p) {
    float4 a = *(const float4*)p;
    float4 b = *(const float4*)(p + 4);
    float t[8] = {a.x, a.y, a.z, a.w, b.x, b.y, b.z, b.w};
    return pack8(t);
}

__device__ inline bf16x8 loadpackneg(const float* p) {
    float4 a = *(const float4*)p;
    float4 b = *(const float4*)(p + 4);
    float t[8] = {-a.x, -a.y, -a.z, -a.w, -b.x, -b.y, -b.z, -b.w};
    return pack8(t);
}

__global__ __launch_bounds__(256) void precompute_kernel(
    const float* __restrict__ strength, const float* __restrict__ str_w,
    const float* __restrict__ str_b,
    const float* __restrict__ q_tbl, const float* __restrict__ k_tbl,
    const float* __restrict__ attn_w1, const float* __restrict__ attn_b1,
    const float* __restrict__ pos_w2, const float* __restrict__ pos_b2,
    const int* __restrict__ embed_id, float* __restrict__ ws)
{
    __shared__ float red[4][64];
    const int t = threadIdx.x;
    const int blk = blockIdx.x;
    const int id = embed_id[0];
    if (blk == 0) {
        const int d = t & 63, part = t >> 6;
        float acc = 0.f;
        for (int i = part * 128; i < part * 128 + 128; ++i)
            acc += strength[i] * str_w[i * 64 + d];
        red[part][d] = acc;
        __syncthreads();
        if (t < 64)
            ws[WS_S + t] = red[0][t] + red[1][t] + red[2][t] + red[3][t] + str_b[t];
    } else if (blk <= 2) {
        const int h = (blk - 1) * 4 + (t >> 6);
        const int j = t & 63;
        const float* W = k_tbl + (size_t)id * TBL;
        float acc = 0.f;
        for (int d = 0; d < 64; ++d) acc += W[d * 64 + j] * attn_w1[d * 8 + h];
        ws[WS_AT + h * 64 + j] = acc;
    } else if (blk <= 4) {
        const int h = (blk - 3) * 4 + (t >> 6);
        const int j = t & 63;
        const float* W = q_tbl + (size_t)id * TBL;
        float acc = 0.f;
        for (int d = 0; d < 64; ++d) acc += W[d * 64 + j] * attn_w1[d * 8 + h];
        ws[WS_BQT + h * 64 + j] = acc;
    } else {
        if (t < 64) {
            const int h = t >> 3, g = t & 7;
            float acc = 0.f;
            for (int d = 0; d < 64; ++d) acc += pos_w2[g * 64 + d] * attn_w1[d * 8 + h];
            ws[WS_CT + t] = acc;
        } else if (t < 72) {
            const int h = t - 64;
            float acc = attn_b1[h];
            for (int d = 0; d < 64; ++d) acc += pos_b2[d] * attn_w1[d * 8 + h];
            ws[WS_C0 + h] = acc;
        }
    }
}

// One wave handles 8 bn (4 iterations of a 16-row pair = 2 bn).
// All LDS buffers are PER-WAVE -> no __syncthreads in this kernel.
// Everything matmul-shaped is MFMA; softmax/combine stays in C-layout
// registers with one xor-16 shuffle per reduction (no vh/hp LDS traffic).
__global__ __launch_bounds__(256, 3) void attn2d_main(
    const float* __restrict__ q, const float* __restrict__ k,
    const float* __restrict__ pos, const float* __restrict__ v_tbl,
    const float* __restrict__ pos_w1, const float* __restrict__ pos_b1,
    const float* __restrict__ pos_w2, const float* __restrict__ pos_b2,
    const float* __restrict__ attn_w2, const float* __restrict__ attn_b2,
    const float* __restrict__ out_w, const float* __restrict__ out_b,
    const int* __restrict__ mask, const int* __restrict__ embed_id,
    const float* __restrict__ ws, float* __restrict__ out)
{
    __shared__ float rhid_lds[4][16 * 12]; // rhid C->A transpose buffer
    __shared__ float x_lds[4][8 * 68];     // x rows for the OUT GEMM

    const int tid  = threadIdx.x;
    const int lane = tid & 63;
    const int wiv  = __builtin_amdgcn_readfirstlane(tid >> 6);
    const int q4   = lane >> 4;    // quad
    const int col  = lane & 15;    // MFMA col / A-row index

    float* rh_w = rhid_lds[wiv];
    float* x_w  = x_lds[wiv];

    const int wid = blockIdx.x * 4 + wiv;      // 0..8191
    const int id  = embed_id[0];

    // ---- persistent B-fragments ----
    // VH: B[k=j][n=d] = Wv[n][j]  (vh = k . Wv^T)
    bf16x8 Bv[4][2];
    #pragma unroll
    for (int t = 0; t < 4; ++t)
        #pragma unroll
        for (int c = 0; c < 2; ++c)
            Bv[t][c] = loadpack(v_tbl + (size_t)id * TBL +
                                (t * 16 + col) * 64 + c * 32 + q4 * 8);
    // HID (K=128 concat): chunks 0-1 = At[n][j], chunks 2-3 = -Bqt[n][j]; n>=8 -> 0
    bf16x8 Bh[4];
    {
        bf16x8 z{};
        #pragma unroll
        for (int c = 0; c < 2; ++c)
            Bh[c] = (col < 8) ? loadpack(ws + WS_AT + col * 64 + c * 32 + q4 * 8) : z;
        #pragma unroll
        for (int c = 0; c < 2; ++c)
            Bh[2 + c] = (col < 8) ? loadpackneg(ws + WS_BQT + col * 64 + c * 32 + q4 * 8) : z;
    }
    // hp->hid: B[k=g][n=h] = Ct[n][g], quad0 only
    bf16x8 Bct{};
    if (q4 == 0 && col < 8) Bct = loadpack(ws + WS_CT + col * 8);
    // logits: B[k=h][n=d] = attn_w2[h*64+d]; pv: B[k=h][n=d] = pos_w2[h*64+d]
    bf16x8 Bw2[4], Bpw2[4];
    {
        bf16x8 z{};
        #pragma unroll
        for (int t = 0; t < 4; ++t) {
            if (q4 == 0) {
                float t0[8], t1[8];
                #pragma unroll
                for (int j = 0; j < 8; ++j) {
                    t0[j] = attn_w2[j * 64 + t * 16 + col];
                    t1[j] = pos_w2[j * 64 + t * 16 + col];
                }
                Bw2[t] = pack8(t0); Bpw2[t] = pack8(t1);
            } else { Bw2[t] = z; Bpw2[t] = z; }
        }
    }

    // ---- per-lane constants (C-layout, 4 d-columns per lane) ----
    float b2a4[4], sb4[4], ob4[4];
    #pragma unroll
    for (int t = 0; t < 4; ++t) {
        b2a4[t] = attn_b2[t * 16 + col];
        sb4[t]  = ws[WS_S + t * 16 + col] + pos_b2[t * 16 + col];
        ob4[t]  = out_b[t * 16 + col];
    }
    const float c0r = (col < 8) ? ws[WS_C0 + col] : 0.f;

    for (int it = 0; it < 4; ++it) {
        const int pair = wid * 4 + it;     // uniform per wave
        const int bn0  = pair * 2;

        // ---- A fragments: k rows (16) and broadcast q rows, f32 -> bf16 ----
        bf16x8 Ak[2], Aq[2];
        #pragma unroll
        for (int c = 0; c < 2; ++c)
            Ak[c] = loadpack(k + ((size_t)pair * 16 + col) * 64 + c * 32 + q4 * 8);
        #pragma unroll
        for (int c = 0; c < 2; ++c)
            Aq[c] = loadpack(q + (size_t)(bn0 + (col >> 3)) * 64 + c * 32 + q4 * 8);

        // mask for my 4 C-rows (rows q4*4..q4*4+3 of the 16-row pair)
        const int4 mk = *(const int4*)(mask + (size_t)pair * 16 + q4 * 4);

        // ---- hp = relu(pos . pos_w1 + b1): A-layout rows on lanes 0-15 ----
        bf16x8 Ahp{};
        if (lane < 16) {
            float4 pp = *(const float4*)(pos + ((size_t)pair * 16 + lane) * 4);
            float hv[8];
            #pragma unroll
            for (int g = 0; g < 8; ++g)
                hv[g] = fmaxf(pos_b1[g] + pp.x * pos_w1[g] + pp.y * pos_w1[8 + g] +
                              pp.z * pos_w1[16 + g] + pp.w * pos_w1[24 + g], 0.f);
            Ahp = pack8(hv);
        }

        // ---- HID: acc[16x16] = k.At - q.Bqt + hp.Ct  (cols 0-7 valid) ----
        f32x4 acch = {0.f, 0.f, 0.f, 0.f};
        acch = __builtin_amdgcn_mfma_f32_16x16x32_bf16(Ak[0], Bh[0], acch, 0, 0, 0);
        acch = __builtin_amdgcn_mfma_f32_16x16x32_bf16(Ak[1], Bh[1], acch, 0, 0, 0);
        acch = __builtin_amdgcn_mfma_f32_16x16x32_bf16(Aq[0], Bh[2], acch, 0, 0, 0);
        acch = __builtin_amdgcn_mfma_f32_16x16x32_bf16(Aq[1], Bh[3], acch, 0, 0, 0);
        acch = __builtin_amdgcn_mfma_f32_16x16x32_bf16(Ahp,   Bct,   acch, 0, 0, 0);
        if (col < 8) {
            #pragma unroll
            for (int r = 0; r < 4; ++r)
                rh_w[(q4 * 4 + r) * 12 + col] = fmaxf(acch[r] + c0r, 0.f);
        }

        // ---- rhid C->A transpose (tiny LDS round trip, wave-internal) ----
        bf16x8 Arh{};
        if (lane < 16) Arh = loadpack(&rh_w[lane * 12]);

        // ---- per d-tile: vh(+pv), logits, masked softmax over v, combine ----
        #pragma unroll
        for (int t = 0; t < 4; ++t) {
            // vhtot[16 x 16] = k.Wv^T + hp.pos_w2 (+ s + pos_b2 later)
            f32x4 av = {0.f, 0.f, 0.f, 0.f};
            av = __builtin_amdgcn_mfma_f32_16x16x32_bf16(Ak[0], Bv[t][0], av, 0, 0, 0);
            av = __builtin_amdgcn_mfma_f32_16x16x32_bf16(Ak[1], Bv[t][1], av, 0, 0, 0);
            av = __builtin_amdgcn_mfma_f32_16x16x32_bf16(Ahp,   Bpw2[t],  av, 0, 0, 0);
            // logits[16 x 16] = rhid.attn_w2
            f32x4 al = {0.f, 0.f, 0.f, 0.f};
            al = __builtin_amdgcn_mfma_f32_16x16x32_bf16(Arh, Bw2[t], al, 0, 0, 0);

            float att[4];
            att[0] = mk.x ? (al[0] + b2a4[t]) : -1e9f;
            att[1] = mk.y ? (al[1] + b2a4[t]) : -1e9f;
            att[2] = mk.z ? (al[2] + b2a4[t]) : -1e9f;
            att[3] = mk.w ? (al[3] + b2a4[t]) : -1e9f;

            float mp = fmaxf(fmaxf(att[0], att[1]), fmaxf(att[2], att[3]));
            float mm = fmaxf(mp, __shfl_xor(mp, 16));
            float e0 = __expf(att[0] - mm), e1 = __expf(att[1] - mm);
            float e2 = __expf(att[2] - mm), e3 = __expf(att[3] - mm);
            float sp = e0 + e1 + e2 + e3;
            float ss = sp + __shfl_xor(sp, 16);
            float xp = e0 * (av[0] + sb4[t]) + e1 * (av[1] + sb4[t])
                     + e2 * (av[2] + sb4[t]) + e3 * (av[3] + sb4[t]);
            float x = (xp + __shfl_xor(xp, 16)) * __builtin_amdgcn_rcpf(ss);
            // lanes with even quad hold the final x for bn = bn0 + (q4>>1)
            if ((q4 & 1) == 0)
                x_w[(it * 2 + (q4 >> 1)) * 68 + t * 16 + col] = x;
        }
    }

    // ---- OUT: out[8 x 64] = x . out_w + out_b, batched over the wave's 8 bn ----
    bf16x8 Ax[2]{};
    if (col < 8) {
        #pragma unroll
        for (int c = 0; c < 2; ++c)
            Ax[c] = loadpack(&x_w[col * 68 + c * 32 + q4 * 8]);
    }
    #pragma unroll
    for (int t = 0; t < 4; ++t) {
        bf16x8 Bo0, Bo1;
        {
            float t0[8], t1[8];
            #pragma unroll
            for (int jj = 0; jj < 8; ++jj) {
                t0[jj] = out_w[(q4 * 8 + jj) * 64 + t * 16 + col];
                t1[jj] = out_w[(32 + q4 * 8 + jj) * 64 + t * 16 + col];
            }
            Bo0 = pack8(t0); Bo1 = pack8(t1);
        }
        f32x4 a = {0.f, 0.f, 0.f, 0.f};
        a = __builtin_amdgcn_mfma_f32_16x16x32_bf16(Ax[0], Bo0, a, 0, 0, 0);
        a = __builtin_amdgcn_mfma_f32_16x16x32_bf16(Ax[1], Bo1, a, 0, 0, 0);
        #pragma unroll
        for (int r = 0; r < 4; ++r) {
            const int row = q4 * 4 + r;
            if (row < 8)
                out[((size_t)wid * 8 + row) * 64 + t * 16 + col] = a[r] + ob4[t];
        }
    }
}

extern "C" void kernel_launch(void* const* d_in, const int* in_sizes, int n_in,
                              void* d_out, int out_size, void* d_ws, size_t ws_size,
                              hipStream_t stream) {
    const float* q        = (const float*)d_in[0];
    const float* k        = (const float*)d_in[1];
    const float* pos      = (const float*)d_in[2];
    const float* strength = (const float*)d_in[3];
    const float* q_tbl    = (const float*)d_in[4];
    const float* k_tbl    = (const float*)d_in[5];
    const float* v_tbl    = (const float*)d_in[6];
    const float* pos_w1   = (const float*)d_in[7];
    const float* pos_b1   = (const float*)d_in[8];
    const float* pos_w2   = (const float*)d_in[9];
    const float* pos_b2   = (const float*)d_in[10];
    const float* attn_w1  = (const float*)d_in[11];
    const float* attn_b1  = (const float*)d_in[12];
    const float* attn_w2  = (const float*)d_in[13];
    const float* attn_b2  = (const float*)d_in[14];
    const float* out_w    = (const float*)d_in[15];
    const float* out_b    = (const float*)d_in[16];
    const float* str_w    = (const float*)d_in[17];
    const float* str_b    = (const float*)d_in[18];
    const int*   mask     = (const int*)d_in[19];
    const int*   embed    = (const int*)d_in[20];
    float* ws  = (float*)d_ws;
    float* out = (float*)d_out;

    hipLaunchKernelGGL(precompute_kernel, dim3(6), dim3(256), 0, stream,
                       strength, str_w, str_b, q_tbl, k_tbl, attn_w1, attn_b1,
                       pos_w2, pos_b2, embed, ws);
    hipLaunchKernelGGL(attn2d_main, dim3(2048), dim3(256), 0, stream,
                       q, k, pos, v_tbl, pos_w1, pos_b1, pos_w2, pos_b2,
                       attn_w2, attn_b2, out_w, out_b, mask, embed, ws, out);
}